// Round 8
// baseline (141.475 us; speedup 1.0000x reference)
//
#include <hip/hip_runtime.h>
#include <stdint.h>

#define NROWS 8192
#define MCOLS 8192
#define DDIM  64

typedef _Float16 half8   __attribute__((ext_vector_type(8)));
typedef float    float8  __attribute__((ext_vector_type(8)));
typedef float    floatx4 __attribute__((ext_vector_type(4)));

// ---------- monotone float <-> uint key (for atomicMax argmax) ----------
__device__ __forceinline__ unsigned f2key(float f) {
  unsigned u = __float_as_uint(f);
  return (u & 0x80000000u) ? ~u : (u | 0x80000000u);
}
__device__ __forceinline__ float key2f(unsigned k) {
  unsigned u = (k & 0x80000000u) ? (k & 0x7fffffffu) : ~k;
  return __uint_as_float(u);
}

// ---------- main pass: block = 4 waves, each wave 32 rows x 256 cols ----------
// Loads x,y fp32 directly in MFMA fragment-lane order and does the
// fp16 hi/lo split (x = h + l*2^-11) in-register; row norms via xor-shuffles.
// 16x16x32 f16 A/B operand layout: m = lane&15, k = c*32 + (lane>>4)*8 + j.
__global__ __launch_bounds__(256, 4) void mfma_tile_kernel(
    const float* __restrict__ x, const float* __restrict__ y,
    unsigned long long* __restrict__ row_key, float* __restrict__ row_sum,
    unsigned long long* __restrict__ col_key, float* __restrict__ col_sum)
{
  __shared__ unsigned long long lkey[256];   // per-block col keys (2 KB)
  __shared__ float              lsum[256];   //                    (1 KB)

  const int wave = threadIdx.x >> 6;
  const int lane = threadIdx.x & 63;
  const int l15  = lane & 15;
  const int grp  = lane >> 4;                // k-group (A/B layout) == row-group g (C/D)
  const int ap0  = blockIdx.y * 8 + wave * 2;       // first of 2 A panels (16 rows each)
  const int ro   = ap0 * 16 + grp * 4;              // first C/D row this lane covers
  const int colbase = blockIdx.x * 256;

  lkey[threadIdx.x] = 0ull;
  lsum[threadIdx.x] = 0.0f;
  __syncthreads();

  // ---- A fragments: load fp32, split hi/lo, compute panel norms ----
  half8 Ah[2][2], Al[2][2];
  float normA[2];
  #pragma unroll
  for (int p = 0; p < 2; ++p) {
    const float* ax = x + (size_t)((ap0 + p) * 16 + l15) * DDIM + grp * 8;
    float8 f0 = *(const float8*)ax;          // chunk c=0: k = grp*8+j
    float8 f1 = *(const float8*)(ax + 32);   // chunk c=1: k = 32+grp*8+j
    float pa = 0.0f;
    #pragma unroll
    for (int j = 0; j < 8; ++j) {
      _Float16 h0 = (_Float16)f0[j];
      _Float16 h1 = (_Float16)f1[j];
      Ah[p][0][j] = h0;  Al[p][0][j] = (_Float16)((f0[j] - (float)h0) * 2048.0f);
      Ah[p][1][j] = h1;  Al[p][1][j] = (_Float16)((f1[j] - (float)h1) * 2048.0f);
      pa = fmaf(f0[j], f0[j], pa);
      pa = fmaf(f1[j], f1[j], pa);
    }
    pa += __shfl_xor(pa, 16);
    pa += __shfl_xor(pa, 32);
    normA[p] = pa;                           // norm of row (ap0+p)*16 + l15
  }

  // redistribute: xne[s] = norm of C/D row ro + ((s>>2)<<4) + (s&3)
  float xne[8], rsum[8], rmax[8]; int ridx[8];
  #pragma unroll
  for (int s = 0; s < 8; ++s) {
    xne[s]  = __shfl(normA[s >> 2], grp * 4 + (s & 3));
    rsum[s] = 0.0f; rmax[s] = -3.4e38f; ridx[s] = 0;
  }

  // ---- jt loop over 16 col panels ----
  for (int jt = 0; jt < 16; ++jt) {
    const int cpg = blockIdx.x * 16 + jt;
    const float* by = y + (size_t)(cpg * 16 + l15) * DDIM + grp * 8;
    float8 g0 = *(const float8*)by;
    float8 g1 = *(const float8*)(by + 32);

    half8 bh0, bh1, bl0, bl1;
    float pb = 0.0f;
    #pragma unroll
    for (int j = 0; j < 8; ++j) {
      _Float16 h0 = (_Float16)g0[j];
      _Float16 h1 = (_Float16)g1[j];
      bh0[j] = h0;  bl0[j] = (_Float16)((g0[j] - (float)h0) * 2048.0f);
      bh1[j] = h1;  bl1[j] = (_Float16)((g1[j] - (float)h1) * 2048.0f);
      pb = fmaf(g0[j], g0[j], pb);
      pb = fmaf(g1[j], g1[j], pb);
    }
    pb += __shfl_xor(pb, 16);
    pb += __shfl_xor(pb, 32);
    const float ync = pb;                    // norm of y-row (col) l15 of this panel
    const int col = colbase + jt * 16 + l15;

    float csum = 0.0f, cmax = -3.4e38f; int cs8 = 0;
    #pragma unroll
    for (int p = 0; p < 2; ++p) {
      floatx4 c1 = {}, c2 = {};
      c1 = __builtin_amdgcn_mfma_f32_16x16x32_f16(Ah[p][0], bh0, c1, 0, 0, 0);
      c1 = __builtin_amdgcn_mfma_f32_16x16x32_f16(Ah[p][1], bh1, c1, 0, 0, 0);
      c2 = __builtin_amdgcn_mfma_f32_16x16x32_f16(Al[p][0], bh0, c2, 0, 0, 0);
      c2 = __builtin_amdgcn_mfma_f32_16x16x32_f16(Al[p][1], bh1, c2, 0, 0, 0);
      c2 = __builtin_amdgcn_mfma_f32_16x16x32_f16(Ah[p][0], bl0, c2, 0, 0, 0);
      c2 = __builtin_amdgcn_mfma_f32_16x16x32_f16(Ah[p][1], bl1, c2, 0, 0, 0);
      #pragma unroll
      for (int r = 0; r < 4; ++r) {
        const int s = p * 4 + r;
        float dot = fmaf(c2[r], (1.0f / 2048.0f), c1[r]);
        float sq  = fmaxf(fmaf(-2.0f, dot, xne[s] + ync), 0.0f);
        float d   = 2.0f - __builtin_amdgcn_sqrtf(sq);
        float e   = __expf(d);
        rsum[s] += e;  csum += e;
        if (d > rmax[s]) ridx[s] = col;      // cols ascend over jt -> first max
        rmax[s] = fmaxf(rmax[s], d);
        if (d > cmax) cs8 = s;               // rows ascend with s -> first max
        cmax = fmaxf(cmax, d);
      }
    }

    // ---- col partial -> LDS atomics (DS pipe) ----
    int crow = ro + ((cs8 >> 2) << 4) + (cs8 & 3);
    unsigned long long ckey =
        ((unsigned long long)f2key(cmax) << 32) |
        (unsigned long long)(unsigned)(~(unsigned)crow);
    atomicMax(&lkey[jt * 16 + l15], ckey);
    atomicAdd(&lsum[jt * 16 + l15], csum);
  }

  // ---- row reduce: one butterfly over the 16 lane-columns ----
  unsigned long long rkk[8];
  #pragma unroll
  for (int s = 0; s < 8; ++s)
    rkk[s] = ((unsigned long long)f2key(rmax[s]) << 32) |
             (unsigned long long)(unsigned)(~(unsigned)ridx[s]);
  #pragma unroll
  for (int off = 1; off < 16; off <<= 1) {
    #pragma unroll
    for (int s = 0; s < 8; ++s) {
      rsum[s] += __shfl_xor(rsum[s], off);
      unsigned long long o = __shfl_xor(rkk[s], off);
      if (o > rkk[s]) rkk[s] = o;
    }
  }
  if (l15 == 0) {
    #pragma unroll
    for (int s = 0; s < 8; ++s) {
      int row = ro + ((s >> 2) << 4) + (s & 3);
      atomicMax(row_key + row, rkk[s]);
      atomicAdd(row_sum + row, rsum[s]);
    }
  }

  // ---- block-level col flush: 1 atomic pair per col ----
  __syncthreads();
  {
    int col = colbase + threadIdx.x;
    atomicMax(col_key + col, lkey[threadIdx.x]);
    atomicAdd(col_sum + col, lsum[threadIdx.x]);
  }
}

// ---------- finalize: unpack keys, mutual test, write outputs ----------
__global__ void finalize_kernel(const unsigned long long* __restrict__ row_key,
                                const float* __restrict__ row_sum,
                                const unsigned long long* __restrict__ col_key,
                                const float* __restrict__ col_sum,
                                float* __restrict__ out)
{
  int j = blockIdx.x * 256 + threadIdx.x;
  if (j >= MCOLS) return;
  unsigned long long ck = col_key[j];
  int   ci   = (int)(~(unsigned)ck);
  float cmax = key2f((unsigned)(ck >> 32));
  float lp_col = cmax - logf(col_sum[j]);

  unsigned long long rk = row_key[ci];
  int   rj   = (int)(~(unsigned)rk);
  float rmax = key2f((unsigned)(rk >> 32));
  float lp_row = rmax - logf(row_sum[ci]);

  int mut = (rj == j);
  out[j]                 = mut ? (lp_row + lp_col) : 0.0f;
  out[MCOLS + 2 * j + 0] = (float)ci;
  out[MCOLS + 2 * j + 1] = (float)j;
  out[3 * MCOLS + j]     = mut ? 1.0f : 0.0f;
}

extern "C" void kernel_launch(void* const* d_in, const int* in_sizes, int n_in,
                              void* d_out, int out_size, void* d_ws, size_t ws_size,
                              hipStream_t stream) {
  const float* x = (const float*)d_in[0];
  const float* y = (const float*)d_in[1];
  float* out = (float*)d_out;

  char* ws = (char*)d_ws;                                             // 192 KB used
  unsigned long long* row_key = (unsigned long long*)(ws);            // 64 KB
  unsigned long long* col_key = (unsigned long long*)(ws + 65536);    // 64 KB
  float* row_sum = (float*)(ws + 131072);                             // 32 KB
  float* col_sum = (float*)(ws + 163840);                             // 32 KB

  // keys -> 0ull, sums -> 0.0f : both all-zero bytes
  hipMemsetAsync(ws, 0, 196608, stream);

  dim3 grid(MCOLS / 256, NROWS / 128);     // 32 x 64 blocks, 256 threads
  mfma_tile_kernel<<<grid, 256, 0, stream>>>(x, y, row_key, row_sum,
                                             col_key, col_sum);
  finalize_kernel<<<32, 256, 0, stream>>>(row_key, row_sum, col_key, col_sum, out);
}